// Round 3
// baseline (1642.971 us; speedup 1.0000x reference)
//
#include <hip/hip_runtime.h>
#include <stdint.h>

#define NGRAPH 512
#define NPG    152
#define NNODES (NGRAPH*NPG)     // 77824
#define DEG    8
#define EPG    (NPG*DEG)        // 1216 edges per graph
#define NEDGE  (NNODES*DEG)     // 622592
#define CCH    192
#define HEADS  6
#define HID    32
#define NSEG   (NPG+EPG)        // 1368 slots = edges + self loops per graph

typedef __attribute__((ext_vector_type(8))) short short8v;
typedef __attribute__((ext_vector_type(4))) float f32x4;

__device__ __forceinline__ unsigned short f2bf(float f){
  union { float f; uint32_t u; } x; x.f = f;
  uint32_t u = x.u;
  return (unsigned short)((u + 0x7fffu + ((u >> 16) & 1u)) >> 16); // RNE
}
__device__ __forceinline__ float bitsf(uint32_t b){
  union { uint32_t u; float f; } x; x.u = b; return x.f;
}
__device__ __forceinline__ void gload_lds16(const void* g, void* l){
  __builtin_amdgcn_global_load_lds((const __attribute__((address_space(1))) void*)g,
                                   (__attribute__((address_space(3))) void*)l, 16, 0, 0);
}

// ---- W1[K][192] f32 -> Wt1[192][128] bf16 ; W2 -> Wt2[192][192] ----
__global__ void wprep_all(const float* __restrict__ W1, const float* __restrict__ W2,
                          unsigned short* __restrict__ Wt1, unsigned short* __restrict__ Wt2){
  int idx = blockIdx.x*256 + threadIdx.x;
  if (idx < CCH*128){
    int c = idx >> 7, k = idx & 127;
    Wt1[idx] = f2bf(W1[k*CCH + c]);
  } else if (idx < CCH*(128+192)){
    int j = idx - CCH*128;
    int c = j/192, k = j - c*192;
    Wt2[j] = f2bf(W2[k*CCH + c]);
  }
}

// ---- GEMM: H[M,192] = A[M,K] @ W  (Bt = W^T bf16 [192][K]) ----
// LDS layout: tile[row][byte db] = global[row][db ^ ((row&7)<<4)]  (16B-chunk XOR swizzle)
// gll staging keeps LDS dest linear and inverse-swizzles the SOURCE (rule #21).
template<int K, bool A_BF16>
__global__ __launch_bounds__(256) void gemm_mfma(const void* __restrict__ Ap,
    const unsigned short* __restrict__ Bt, unsigned short* __restrict__ H){
  __shared__ unsigned short lA[64*K];
  __shared__ unsigned short lB[96*K];
  const int t  = threadIdx.x;
  const int m0 = blockIdx.x*64, c0 = blockIdx.y*96;

  if (A_BF16){
    const unsigned short* A = (const unsigned short*)Ap + (size_t)m0*K;
    const int CH = 64*K/8;                 // 16B chunks (multiple of 256)
    for (int i=t; i<CH; i+=256){
      int o   = i*16;
      int row = o / (2*K);
      int db  = o - row*(2*K);
      int sc  = (db>>4) ^ (row&7);
      gload_lds16(A + (size_t)row*K + sc*8, lA + (size_t)(i-(t&63))*8);
    }
  } else {
    const float* A = (const float*)Ap;
    const int KC = K/8;
    for (int i=t; i<64*KC; i+=256){
      int row = i/KC, c8 = i - row*KC;
      const float* p = A + (size_t)(m0+row)*K + c8*8;
      float4 v0 = *(const float4*)p;
      float4 v1 = *(const float4*)(p+4);
      short8v pk;
      pk[0]=(short)f2bf(v0.x); pk[1]=(short)f2bf(v0.y); pk[2]=(short)f2bf(v0.z); pk[3]=(short)f2bf(v0.w);
      pk[4]=(short)f2bf(v1.x); pk[5]=(short)f2bf(v1.y); pk[6]=(short)f2bf(v1.z); pk[7]=(short)f2bf(v1.w);
      *(short8v*)((char*)lA + row*(2*K) + ((c8*16) ^ ((row&7)<<4))) = pk;
    }
  }
  {
    const unsigned short* Bg = Bt + (size_t)c0*K;
    const int CH = 96*K/8;
    for (int i=t; i<CH; i+=256){
      int o   = i*16;
      int row = o / (2*K);
      int db  = o - row*(2*K);
      int sc  = (db>>4) ^ (row&7);
      gload_lds16(Bg + (size_t)row*K + sc*8, lB + (size_t)(i-(t&63))*8);
    }
  }
  __syncthreads();

  const int wid = t>>6, l = t&63;
  const int wr = wid>>1, wc = wid&1;      // 2x2 wave grid: 32 rows x 48 cols each
  const int r16 = l&15, kq = l>>4;
  f32x4 acc[2][3] = {};
  #pragma unroll
  for (int kk=0; kk<K/32; kk++){
    const int chunk = kk*4 + kq;
    short8v af[2], bf[3];
    #pragma unroll
    for (int m=0;m<2;m++){
      int row = wr*32 + m*16 + r16;
      af[m] = *(const short8v*)((const char*)lA + row*(2*K) + ((chunk*16) ^ ((row&7)<<4)));
    }
    #pragma unroll
    for (int n=0;n<3;n++){
      int col = wc*48 + n*16 + r16;
      bf[n] = *(const short8v*)((const char*)lB + col*(2*K) + ((chunk*16) ^ ((col&7)<<4)));
    }
    #pragma unroll
    for (int m=0;m<2;m++)
      #pragma unroll
      for (int n=0;n<3;n++)
        acc[m][n] = __builtin_amdgcn_mfma_f32_16x16x32_bf16(af[m], bf[n], acc[m][n], 0,0,0);
  }
  const int crow = (l>>4)*4;   // C/D: col = lane&15, row = (lane>>4)*4 + reg  [m89]
  #pragma unroll
  for (int m=0;m<2;m++){
    #pragma unroll
    for (int n=0;n<3;n++){
      int colg = c0 + wc*48 + n*16 + r16;
      #pragma unroll
      for (int r=0;r<4;r++){
        int rowg = m0 + wr*32 + m*16 + crow + r;
        H[(size_t)rowg*CCH + colg] = f2bf(acc[m][n][r]);
      }
    }
  }
}

// ---- fused GAT edge softmax + aggregation + bias + ELU + GraphNorm ----
// one block per (graph, head); fully edge-parallel (no CSR, no serial per-dst loops).
// softmax computed WITHOUT max subtraction (exactly invariant; logits are O(1) here).
template<bool OUT_BF16>
__global__ __launch_bounds__(256) void gat_edge(
    const unsigned short* __restrict__ H,
    const int* __restrict__ esrc, const int* __restrict__ edst,
    const float* __restrict__ a_src, const float* __restrict__ a_dst,
    const float* __restrict__ bias, const float* __restrict__ gw,
    const float* __restrict__ gb, const float* __restrict__ gms,
    void* __restrict__ OUTp)
{
  __shared__ float hN[NPG*HID];          // h for this head, f32
  __shared__ float outA[NPG*HID];        // aggregation accumulators
  __shared__ float eVal[NSEG];           // exp(leakyrelu(e)) per slot
  __shared__ int   ePack[NSEG];          // src | dst<<16
  __shared__ float denom[NPG];
  __shared__ float als[NPG], ald[NPG];
  __shared__ float ps[8][32];
  __shared__ float mred[32], vred[32];

  const int t    = threadIdx.x;
  const int g    = blockIdx.x & 511;
  const int hd   = blockIdx.x >> 9;
  const int base = g*NPG;
  const int lane32 = t & 31, grp = t >> 5;

  for (int i=t; i<NPG*HID; i+=256) outA[i] = 0.f;
  if (t < NPG) denom[t] = 0.f;

  // load h_head (bf16 -> f32)
  for (int i=t; i<NPG*HID/8; i+=256){
    int n = i>>2, c8 = i&3;
    int4 v = *(const int4*)(H + (size_t)(base+n)*CCH + hd*HID + c8*8);
    uint32_t w0=(uint32_t)v.x, w1=(uint32_t)v.y, w2=(uint32_t)v.z, w3=(uint32_t)v.w;
    float* dst = &hN[n*HID + c8*8];
    float4 lo = { bitsf(w0<<16), bitsf(w0&0xffff0000u), bitsf(w1<<16), bitsf(w1&0xffff0000u) };
    float4 hi = { bitsf(w2<<16), bitsf(w2&0xffff0000u), bitsf(w3<<16), bitsf(w3&0xffff0000u) };
    *(float4*)dst = lo;
    *(float4*)(dst+4) = hi;
  }
  __syncthreads();

  // attention logits per node: 8 groups of 32 lanes; lane = channel
  const float avs = a_src[hd*HID + lane32];
  const float avd = a_dst[hd*HID + lane32];
  #pragma unroll
  for (int k=0;k<19;k++){
    int n = grp + (k<<3);
    float hv = hN[n*HID + lane32];
    float s1 = hv*avs, s2 = hv*avd;
    #pragma unroll
    for (int m=16;m>0;m>>=1){ s1 += __shfl_xor(s1, m, 32); s2 += __shfl_xor(s2, m, 32); }
    if (lane32==0){ als[n]=s1; ald[n]=s2; }
  }
  __syncthreads();

  // edge-parallel: exp(leakyrelu(als[s]+ald[d])), accumulate denom[d]
  for (int i=t; i<EPG; i+=256){
    int s = esrc[g*EPG + i] - base;
    int d = edst[g*EPG + i] - base;
    float e = als[s] + ald[d];
    e = (e>0.f) ? e : 0.2f*e;
    float ex = __expf(e);
    eVal[i] = ex; ePack[i] = s | (d<<16);
    atomicAdd(&denom[d], ex);
  }
  if (t < NPG){                          // self loop slots
    float e = als[t] + ald[t];
    e = (e>0.f) ? e : 0.2f*e;
    float ex = __expf(e);
    eVal[EPG+t] = ex; ePack[EPG+t] = t | (t<<16);
    atomicAdd(&denom[t], ex);
  }
  __syncthreads();

  if (t < NPG) denom[t] = 1.f/denom[t];  // invert while aggregation runs (no reader yet)

  // edge-parallel aggregation: slot = it*8+grp, ch = lane32 (conflict-free hN read)
  #pragma unroll 4
  for (int it=0; it<NSEG/8; ++it){
    int slot = it*8 + grp;
    int p = ePack[slot];
    int s = p & 0xffff, d = p >> 16;
    atomicAdd(&outA[d*HID + lane32], eVal[slot]*hN[s*HID + lane32]);
  }
  __syncthreads();

  // epilogue: /denom + bias + ELU + GraphNorm, dst-parallel
  const float bsv = bias[hd*HID + lane32];
  const float wv  = gw [hd*HID + lane32];
  const float gbv = gb [hd*HID + lane32];
  const float msv = gms[hd*HID + lane32];
  float acc[19];
  #pragma unroll
  for (int k=0;k<19;k++){
    int n = grp + (k<<3);
    float x = outA[n*HID + lane32]*denom[n] + bsv;
    acc[k] = (x>0.f) ? x : (__expf(x)-1.f);
  }

  float psum = 0.f;
  #pragma unroll
  for (int k=0;k<19;k++) psum += acc[k];
  ps[grp][lane32] = psum;
  __syncthreads();
  if (t < 32){
    float s=0.f;
    #pragma unroll
    for (int q=0;q<8;q++) s += ps[q][t];
    mred[t] = s * (1.f/152.f);
  }
  __syncthreads();
  const float mean = mred[lane32];
  float p2 = 0.f;
  #pragma unroll
  for (int k=0;k<19;k++){ acc[k] -= mean*msv; p2 += acc[k]*acc[k]; }
  ps[grp][lane32] = p2;
  __syncthreads();
  if (t < 32){
    float s=0.f;
    #pragma unroll
    for (int q=0;q<8;q++) s += ps[q][t];
    vred[t] = rsqrtf(s*(1.f/152.f) + 1e-5f);
  }
  __syncthreads();
  const float rs = vred[lane32];
  #pragma unroll
  for (int k=0;k<19;k++){
    int n = grp + (k<<3);
    float v = acc[k]*rs*wv + gbv;
    size_t oidx = (size_t)(base+n)*CCH + hd*HID + lane32;
    if (OUT_BF16) ((unsigned short*)OUTp)[oidx] = f2bf(v);
    else          ((float*)OUTp)[oidx] = v;
  }
}

extern "C" void kernel_launch(void* const* d_in, const int* in_sizes, int n_in,
                              void* d_out, int out_size, void* d_ws, size_t ws_size,
                              hipStream_t stream){
  (void)in_sizes; (void)n_in; (void)out_size; (void)ws_size;
  const float* x    = (const float*)d_in[0];
  const int*   ei   = (const int*)  d_in[1];
  const float* W1   = (const float*)d_in[3];
  const float* as1  = (const float*)d_in[4];
  const float* ad1  = (const float*)d_in[5];
  const float* b1   = (const float*)d_in[6];
  const float* W2   = (const float*)d_in[7];
  const float* as2  = (const float*)d_in[8];
  const float* ad2  = (const float*)d_in[9];
  const float* b2   = (const float*)d_in[10];
  const float* gw1  = (const float*)d_in[11];
  const float* gb1  = (const float*)d_in[12];
  const float* gms1 = (const float*)d_in[13];
  const float* gw2  = (const float*)d_in[14];
  const float* gb2  = (const float*)d_in[15];
  const float* gms2 = (const float*)d_in[16];
  const int* esrc = ei;
  const int* edst = ei + NEDGE;

  char* ws = (char*)d_ws;
  unsigned short* Hbuf = (unsigned short*)ws;                               // [N,192] bf16
  unsigned short* Obuf = (unsigned short*)(ws + (size_t)NNODES*CCH*2);      // [N,192] bf16
  unsigned short* Wt1  = (unsigned short*)(ws + (size_t)NNODES*CCH*4);      // [192,128] bf16
  unsigned short* Wt2  = Wt1 + CCH*128;                                     // [192,192] bf16

  wprep_all<<<(CCH*(128+192)+255)/256, 256, 0, stream>>>(W1, W2, Wt1, Wt2);

  gemm_mfma<128,false><<<dim3(NNODES/64,2), 256, 0, stream>>>((const void*)x, Wt1, Hbuf);
  gat_edge<true><<<NGRAPH*HEADS, 256, 0, stream>>>(Hbuf, esrc, edst, as1, ad1, b1, gw1, gb1, gms1, (void*)Obuf);
  gemm_mfma<192,true><<<dim3(NNODES/64,2), 256, 0, stream>>>((const void*)Obuf, Wt2, Hbuf);
  gat_edge<false><<<NGRAPH*HEADS, 256, 0, stream>>>(Hbuf, esrc, edst, as2, ad2, b2, gw2, gb2, gms2, d_out);
}

// Round 4
// 285.892 us; speedup vs baseline: 5.7468x; 5.7468x over previous
//
#include <hip/hip_runtime.h>
#include <stdint.h>

#define NGRAPH 512
#define NPG    152
#define NNODES (NGRAPH*NPG)     // 77824
#define DEG    8
#define EPG    (NPG*DEG)        // 1216 edges per graph
#define NEDGE  (NNODES*DEG)     // 622592
#define CCH    192
#define HEADS  6
#define HID    32
#define NSEG   (NPG+EPG)        // 1368 slots = edges + self loops per graph
#define HSTR   36               // padded hN row stride (floats) to de-alias banks

typedef __attribute__((ext_vector_type(8))) short short8v;
typedef __attribute__((ext_vector_type(4))) float f32x4;
typedef __attribute__((ext_vector_type(4))) unsigned short ushort4v;

__device__ __forceinline__ unsigned short f2bf(float f){
  union { float f; uint32_t u; } x; x.f = f;
  uint32_t u = x.u;
  return (unsigned short)((u + 0x7fffu + ((u >> 16) & 1u)) >> 16); // RNE
}
__device__ __forceinline__ float bitsf(uint32_t b){
  union { uint32_t u; float f; } x; x.u = b; return x.f;
}
__device__ __forceinline__ void gload_lds16(const void* g, void* l){
  __builtin_amdgcn_global_load_lds((const __attribute__((address_space(1))) void*)g,
                                   (__attribute__((address_space(3))) void*)l, 16, 0, 0);
}

// ---- W1[K][192] f32 -> Wt1[192][128] bf16 ; W2 -> Wt2[192][192] ----
__global__ void wprep_all(const float* __restrict__ W1, const float* __restrict__ W2,
                          unsigned short* __restrict__ Wt1, unsigned short* __restrict__ Wt2){
  int idx = blockIdx.x*256 + threadIdx.x;
  if (idx < CCH*128){
    int c = idx >> 7, k = idx & 127;
    Wt1[idx] = f2bf(W1[k*CCH + c]);
  } else if (idx < CCH*(128+192)){
    int j = idx - CCH*128;
    int c = j/192, k = j - c*192;
    Wt2[j] = f2bf(W2[k*CCH + c]);
  }
}

// ---- GEMM: H[M,192] = A[M,K] @ W  (Bt = W^T bf16 [192][K]) ---- (unchanged from R1)
template<int K, bool A_BF16>
__global__ __launch_bounds__(256) void gemm_mfma(const void* __restrict__ Ap,
    const unsigned short* __restrict__ Bt, unsigned short* __restrict__ H){
  __shared__ unsigned short lA[64*K];
  __shared__ unsigned short lB[96*K];
  const int t  = threadIdx.x;
  const int m0 = blockIdx.x*64, c0 = blockIdx.y*96;

  if (A_BF16){
    const unsigned short* A = (const unsigned short*)Ap + (size_t)m0*K;
    const int CH = 64*K/8;
    for (int i=t; i<CH; i+=256){
      int o   = i*16;
      int row = o / (2*K);
      int db  = o - row*(2*K);
      int sc  = (db>>4) ^ (row&7);
      gload_lds16(A + (size_t)row*K + sc*8, lA + (size_t)(i-(t&63))*8);
    }
  } else {
    const float* A = (const float*)Ap;
    const int KC = K/8;
    for (int i=t; i<64*KC; i+=256){
      int row = i/KC, c8 = i - row*KC;
      const float* p = A + (size_t)(m0+row)*K + c8*8;
      float4 v0 = *(const float4*)p;
      float4 v1 = *(const float4*)(p+4);
      short8v pk;
      pk[0]=(short)f2bf(v0.x); pk[1]=(short)f2bf(v0.y); pk[2]=(short)f2bf(v0.z); pk[3]=(short)f2bf(v0.w);
      pk[4]=(short)f2bf(v1.x); pk[5]=(short)f2bf(v1.y); pk[6]=(short)f2bf(v1.z); pk[7]=(short)f2bf(v1.w);
      *(short8v*)((char*)lA + row*(2*K) + ((c8*16) ^ ((row&7)<<4))) = pk;
    }
  }
  {
    const unsigned short* Bg = Bt + (size_t)c0*K;
    const int CH = 96*K/8;
    for (int i=t; i<CH; i+=256){
      int o   = i*16;
      int row = o / (2*K);
      int db  = o - row*(2*K);
      int sc  = (db>>4) ^ (row&7);
      gload_lds16(Bg + (size_t)row*K + sc*8, lB + (size_t)(i-(t&63))*8);
    }
  }
  __syncthreads();

  const int wid = t>>6, l = t&63;
  const int wr = wid>>1, wc = wid&1;
  const int r16 = l&15, kq = l>>4;
  f32x4 acc[2][3] = {};
  #pragma unroll
  for (int kk=0; kk<K/32; kk++){
    const int chunk = kk*4 + kq;
    short8v af[2], bf[3];
    #pragma unroll
    for (int m=0;m<2;m++){
      int row = wr*32 + m*16 + r16;
      af[m] = *(const short8v*)((const char*)lA + row*(2*K) + ((chunk*16) ^ ((row&7)<<4)));
    }
    #pragma unroll
    for (int n=0;n<3;n++){
      int col = wc*48 + n*16 + r16;
      bf[n] = *(const short8v*)((const char*)lB + col*(2*K) + ((chunk*16) ^ ((col&7)<<4)));
    }
    #pragma unroll
    for (int m=0;m<2;m++)
      #pragma unroll
      for (int n=0;n<3;n++)
        acc[m][n] = __builtin_amdgcn_mfma_f32_16x16x32_bf16(af[m], bf[n], acc[m][n], 0,0,0);
  }
  const int crow = (l>>4)*4;
  #pragma unroll
  for (int m=0;m<2;m++){
    #pragma unroll
    for (int n=0;n<3;n++){
      int colg = c0 + wc*48 + n*16 + r16;
      #pragma unroll
      for (int r=0;r<4;r++){
        int rowg = m0 + wr*32 + m*16 + crow + r;
        H[(size_t)rowg*CCH + colg] = f2bf(acc[m][n][r]);
      }
    }
  }
}

// ---- fused GAT: CSR build (int atomics) + fused denom/aggregation (no fp atomics,
//      no serial softmax) + bias + ELU + GraphNorm.  One block per (graph, head). ----
template<bool OUT_BF16>
__global__ __launch_bounds__(256) void gat_edge(
    const unsigned short* __restrict__ H,
    const int* __restrict__ esrc, const int* __restrict__ edst,
    const float* __restrict__ a_src, const float* __restrict__ a_dst,
    const float* __restrict__ bias, const float* __restrict__ gw,
    const float* __restrict__ gb, const float* __restrict__ gms,
    void* __restrict__ OUTp)
{
  __shared__ float hN[NPG*HSTR];     // 21.9 KB, padded stride
  __shared__ float score[NSEG];      // exp(lrelu(e)) per CSR slot
  __shared__ int   ssrc[NSEG];
  __shared__ int   cnt[256];
  __shared__ int   woff[NPG];
  __shared__ float als[NPG], ald[NPG];
  __shared__ float4 ps[8][8];
  __shared__ float4 mred4[8], vred4[8];

  const int t    = threadIdx.x;
  const int g    = blockIdx.x & 511;
  const int hd   = blockIdx.x >> 9;
  const int base = g*NPG;
  const int lane32 = t & 31, grp = t >> 5;

  cnt[t] = (t < NPG) ? 1 : 0;        // self loop pre-counted

  // phase A: load h_head (bf16 -> f32), padded stride
  for (int i=t; i<NPG*4; i+=256){
    int n = i>>2, c8c = i&3;
    int4 v = *(const int4*)(H + (size_t)(base+n)*CCH + hd*HID + c8c*8);
    uint32_t w0=(uint32_t)v.x, w1=(uint32_t)v.y, w2=(uint32_t)v.z, w3=(uint32_t)v.w;
    float* dst = &hN[n*HSTR + c8c*8];
    float4 lo = { bitsf(w0<<16), bitsf(w0&0xffff0000u), bitsf(w1<<16), bitsf(w1&0xffff0000u) };
    float4 hi = { bitsf(w2<<16), bitsf(w2&0xffff0000u), bitsf(w3<<16), bitsf(w3&0xffff0000u) };
    *(float4*)dst = lo;
    *(float4*)(dst+4) = hi;
  }
  __syncthreads();

  // phase B: in-degree counting (native int LDS atomics) + attention logits
  for (int i=t; i<EPG; i+=256){
    int d = edst[g*EPG + i] - base;
    atomicAdd(&cnt[d], 1);
  }
  const float avs = a_src[hd*HID + lane32];
  const float avd = a_dst[hd*HID + lane32];
  #pragma unroll
  for (int k=0;k<19;k++){
    int n = grp + (k<<3);
    float hv = hN[n*HSTR + lane32];
    float s1 = hv*avs, s2 = hv*avd;
    #pragma unroll
    for (int m=16;m>0;m>>=1){ s1 += __shfl_xor(s1, m, 32); s2 += __shfl_xor(s2, m, 32); }
    if (lane32==0){ als[n]=s1; ald[n]=s2; }
  }
  __syncthreads();

  // phase C1: inclusive scan of cnt[0..255] (Hillis-Steele)
  for (int off=1; off<256; off<<=1){
    int a = cnt[t];
    int b = (t>=off) ? cnt[t-off] : 0;
    __syncthreads();
    cnt[t] = a + b;
    __syncthreads();
  }
  if (t<NPG) woff[t] = (t==0) ? 0 : cnt[t-1];
  __syncthreads();

  // phase C2: scatter edges into CSR with ex = exp(leakyrelu(logit))
  for (int i=t; i<EPG; i+=256){
    int s = esrc[g*EPG + i] - base;
    int d = edst[g*EPG + i] - base;
    float e = als[s] + ald[d];
    e = (e>0.f) ? e : 0.2f*e;
    int pos = atomicAdd(&woff[d], 1);         // ds_add_rtn_u32 (native)
    score[pos] = __expf(e); ssrc[pos] = s;
  }
  if (t < NPG){
    float e = als[t] + ald[t];
    e = (e>0.f) ? e : 0.2f*e;
    int pos = atomicAdd(&woff[t], 1);
    score[pos] = __expf(e); ssrc[pos] = t;
  }
  __syncthreads();

  // phase D: fused denom + aggregation. 32 owners x 8 lanes (lane=channel quad).
  const int sub = (lane32>>3)&3;     // 0..3
  const int c8  = lane32&7;          // channel quad 0..7
  const int o   = grp*4 + sub;       // owner 0..31
  float4 acc[5]; float den[5]; int stq[5], lnq[5];
  #pragma unroll
  for (int q=0;q<5;q++){
    int n = o + q*32;
    int st=0, en=0;
    if (n < NPG){ st = (n==0)?0:cnt[n-1]; en = cnt[n]; }
    stq[q]=st; lnq[q]=en-st;
    acc[q] = float4{0.f,0.f,0.f,0.f}; den[q]=0.f;
  }
  #pragma unroll
  for (int q=0;q<5;q++){
    int st=stq[q], len=lnq[q];
    int rounds = (len+3)>>2;
    for (int r=0;r<rounds;++r){
      #pragma unroll
      for (int u=0;u<4;u++){
        int j = r*4+u;
        int idx = st + ((j<len)? j : 0);
        float ex = score[idx];
        if (j>=len) ex = 0.f;
        int s = ssrc[idx];
        const float4 hv = *(const float4*)&hN[s*HSTR + c8*4];
        den[q] += ex;
        acc[q].x = fmaf(ex, hv.x, acc[q].x);
        acc[q].y = fmaf(ex, hv.y, acc[q].y);
        acc[q].z = fmaf(ex, hv.z, acc[q].z);
        acc[q].w = fmaf(ex, hv.w, acc[q].w);
      }
    }
  }

  // epilogue: /denom + bias + ELU, then GraphNorm over 152 nodes per channel
  const int cb = hd*HID + c8*4;
  const float4 bs4 = *(const float4*)&bias[cb];
  const float4 gw4 = *(const float4*)&gw[cb];
  const float4 gb4 = *(const float4*)&gb[cb];
  const float4 ms4 = *(const float4*)&gms[cb];

  float4 outv[5];
  float4 psum = {0.f,0.f,0.f,0.f};
  #pragma unroll
  for (int q=0;q<5;q++){
    int n = o + q*32;
    float4 x = {0.f,0.f,0.f,0.f};
    if (n < NPG){
      float inv = 1.f/den[q];
      x.x = acc[q].x*inv + bs4.x;  x.y = acc[q].y*inv + bs4.y;
      x.z = acc[q].z*inv + bs4.z;  x.w = acc[q].w*inv + bs4.w;
      x.x = (x.x>0.f)?x.x:(__expf(x.x)-1.f);
      x.y = (x.y>0.f)?x.y:(__expf(x.y)-1.f);
      x.z = (x.z>0.f)?x.z:(__expf(x.z)-1.f);
      x.w = (x.w>0.f)?x.w:(__expf(x.w)-1.f);
      psum.x+=x.x; psum.y+=x.y; psum.z+=x.z; psum.w+=x.w;
    }
    outv[q]=x;
  }
  psum.x += __shfl_xor(psum.x, 8, 32); psum.y += __shfl_xor(psum.y, 8, 32);
  psum.z += __shfl_xor(psum.z, 8, 32); psum.w += __shfl_xor(psum.w, 8, 32);
  psum.x += __shfl_xor(psum.x,16, 32); psum.y += __shfl_xor(psum.y,16, 32);
  psum.z += __shfl_xor(psum.z,16, 32); psum.w += __shfl_xor(psum.w,16, 32);
  if (sub==0) ps[grp][c8] = psum;
  __syncthreads();
  if (t < 8){
    float4 m = {0.f,0.f,0.f,0.f};
    #pragma unroll
    for (int q=0;q<8;q++){ float4 v=ps[q][t]; m.x+=v.x; m.y+=v.y; m.z+=v.z; m.w+=v.w; }
    m.x*=(1.f/152.f); m.y*=(1.f/152.f); m.z*=(1.f/152.f); m.w*=(1.f/152.f);
    mred4[t] = m;
  }
  __syncthreads();
  const float4 mean4 = mred4[c8];
  float4 v2 = {0.f,0.f,0.f,0.f};
  #pragma unroll
  for (int q=0;q<5;q++){
    int n = o + q*32;
    if (n < NPG){
      outv[q].x -= mean4.x*ms4.x; outv[q].y -= mean4.y*ms4.y;
      outv[q].z -= mean4.z*ms4.z; outv[q].w -= mean4.w*ms4.w;
      v2.x = fmaf(outv[q].x,outv[q].x,v2.x); v2.y = fmaf(outv[q].y,outv[q].y,v2.y);
      v2.z = fmaf(outv[q].z,outv[q].z,v2.z); v2.w = fmaf(outv[q].w,outv[q].w,v2.w);
    }
  }
  v2.x += __shfl_xor(v2.x, 8, 32); v2.y += __shfl_xor(v2.y, 8, 32);
  v2.z += __shfl_xor(v2.z, 8, 32); v2.w += __shfl_xor(v2.w, 8, 32);
  v2.x += __shfl_xor(v2.x,16, 32); v2.y += __shfl_xor(v2.y,16, 32);
  v2.z += __shfl_xor(v2.z,16, 32); v2.w += __shfl_xor(v2.w,16, 32);
  if (sub==0) ps[grp][c8] = v2;
  __syncthreads();
  if (t < 8){
    float4 s = {0.f,0.f,0.f,0.f};
    #pragma unroll
    for (int q=0;q<8;q++){ float4 v=ps[q][t]; s.x+=v.x; s.y+=v.y; s.z+=v.z; s.w+=v.w; }
    float4 rv;
    rv.x = rsqrtf(s.x*(1.f/152.f)+1e-5f); rv.y = rsqrtf(s.y*(1.f/152.f)+1e-5f);
    rv.z = rsqrtf(s.z*(1.f/152.f)+1e-5f); rv.w = rsqrtf(s.w*(1.f/152.f)+1e-5f);
    vred4[t] = rv;
  }
  __syncthreads();
  const float4 rs4 = vred4[c8];
  #pragma unroll
  for (int q=0;q<5;q++){
    int n = o + q*32;
    if (n < NPG){
      float4 x = outv[q];
      x.x = x.x*rs4.x*gw4.x + gb4.x;  x.y = x.y*rs4.y*gw4.y + gb4.y;
      x.z = x.z*rs4.z*gw4.z + gb4.z;  x.w = x.w*rs4.w*gw4.w + gb4.w;
      size_t oidx = (size_t)(base+n)*CCH + cb;
      if (OUT_BF16){
        ushort4v pk = { f2bf(x.x), f2bf(x.y), f2bf(x.z), f2bf(x.w) };
        *(ushort4v*)((unsigned short*)OUTp + oidx) = pk;
      } else {
        *(float4*)((float*)OUTp + oidx) = x;
      }
    }
  }
}

extern "C" void kernel_launch(void* const* d_in, const int* in_sizes, int n_in,
                              void* d_out, int out_size, void* d_ws, size_t ws_size,
                              hipStream_t stream){
  (void)in_sizes; (void)n_in; (void)out_size; (void)ws_size;
  const float* x    = (const float*)d_in[0];
  const int*   ei   = (const int*)  d_in[1];
  const float* W1   = (const float*)d_in[3];
  const float* as1  = (const float*)d_in[4];
  const float* ad1  = (const float*)d_in[5];
  const float* b1   = (const float*)d_in[6];
  const float* W2   = (const float*)d_in[7];
  const float* as2  = (const float*)d_in[8];
  const float* ad2  = (const float*)d_in[9];
  const float* b2   = (const float*)d_in[10];
  const float* gw1  = (const float*)d_in[11];
  const float* gb1  = (const float*)d_in[12];
  const float* gms1 = (const float*)d_in[13];
  const float* gw2  = (const float*)d_in[14];
  const float* gb2  = (const float*)d_in[15];
  const float* gms2 = (const float*)d_in[16];
  const int* esrc = ei;
  const int* edst = ei + NEDGE;

  char* ws = (char*)d_ws;
  unsigned short* Hbuf = (unsigned short*)ws;                               // [N,192] bf16
  unsigned short* Obuf = (unsigned short*)(ws + (size_t)NNODES*CCH*2);      // [N,192] bf16
  unsigned short* Wt1  = (unsigned short*)(ws + (size_t)NNODES*CCH*4);      // [192,128] bf16
  unsigned short* Wt2  = Wt1 + CCH*128;                                     // [192,192] bf16

  wprep_all<<<(CCH*(128+192)+255)/256, 256, 0, stream>>>(W1, W2, Wt1, Wt2);

  gemm_mfma<128,false><<<dim3(NNODES/64,2), 256, 0, stream>>>((const void*)x, Wt1, Hbuf);
  gat_edge<true><<<NGRAPH*HEADS, 256, 0, stream>>>(Hbuf, esrc, edst, as1, ad1, b1, gw1, gb1, gms1, (void*)Obuf);
  gemm_mfma<192,true><<<dim3(NNODES/64,2), 256, 0, stream>>>((const void*)Obuf, Wt2, Hbuf);
  gat_edge<false><<<NGRAPH*HEADS, 256, 0, stream>>>(Hbuf, esrc, edst, as2, ad2, b2, gw2, gb2, gms2, d_out);
}

// Round 5
// 232.843 us; speedup vs baseline: 7.0561x; 1.2278x over previous
//
#include <hip/hip_runtime.h>
#include <stdint.h>

#define NGRAPH 512
#define NPG    152
#define NNODES (NGRAPH*NPG)     // 77824
#define DEG    8
#define EPG    (NPG*DEG)        // 1216 edges per graph
#define NEDGE  (NNODES*DEG)     // 622592
#define CCH    192
#define HEADS  6
#define HID    32
#define NSEG   (NPG+EPG)        // 1368 slots = edges + self loops per graph
#define HSTR   36               // padded hN row stride (floats)
#define CNTP   160              // padded gcnt row (ints)

typedef __attribute__((ext_vector_type(8))) short short8v;
typedef __attribute__((ext_vector_type(4))) float f32x4;
typedef __attribute__((ext_vector_type(4))) unsigned short ushort4v;

__device__ __forceinline__ unsigned short f2bf(float f){
  union { float f; uint32_t u; } x; x.f = f;
  uint32_t u = x.u;
  return (unsigned short)((u + 0x7fffu + ((u >> 16) & 1u)) >> 16); // RNE
}
__device__ __forceinline__ float bitsf(uint32_t b){
  union { uint32_t u; float f; } x; x.u = b; return x.f;
}
__device__ __forceinline__ void gload_lds16(const void* g, void* l){
  __builtin_amdgcn_global_load_lds((const __attribute__((address_space(1))) void*)g,
                                   (__attribute__((address_space(3))) void*)l, 16, 0, 0);
}

// ---- W1[K][192] f32 -> Wt1[192][128] bf16 ; W2 -> Wt2[192][192] ----
__global__ void wprep_all(const float* __restrict__ W1, const float* __restrict__ W2,
                          unsigned short* __restrict__ Wt1, unsigned short* __restrict__ Wt2){
  int idx = blockIdx.x*256 + threadIdx.x;
  if (idx < CCH*128){
    int c = idx >> 7, k = idx & 127;
    Wt1[idx] = f2bf(W1[k*CCH + c]);
  } else if (idx < CCH*(128+192)){
    int j = idx - CCH*128;
    int c = j/192, k = j - c*192;
    Wt2[j] = f2bf(W2[k*CCH + c]);
  }
}

// ---- once-per-graph CSR build: dst-sorted src ids (u16) + offsets ----
__global__ __launch_bounds__(256) void csr_build(const int* __restrict__ esrc,
    const int* __restrict__ edst, unsigned short* __restrict__ gsrc,
    int* __restrict__ gcnt){
  __shared__ int cnt[256];
  __shared__ int woff[NPG];
  __shared__ __align__(16) unsigned short slots[NSEG];
  const int t = threadIdx.x, g = blockIdx.x, base = g*NPG;

  cnt[t] = (t < NPG) ? 1 : 0;            // self loop pre-counted
  __syncthreads();

  int es[5], ed[5];
  #pragma unroll
  for (int u=0;u<5;u++){
    int i = t + u*256;
    if (i < EPG){
      es[u] = esrc[g*EPG + i] - base;
      ed[u] = edst[g*EPG + i] - base;
      atomicAdd(&cnt[ed[u]], 1);
    }
  }
  __syncthreads();
  for (int off=1; off<256; off<<=1){
    int a = cnt[t];
    int b = (t>=off) ? cnt[t-off] : 0;
    __syncthreads();
    cnt[t] = a + b;
    __syncthreads();
  }
  if (t < NPG){
    int st = (t==0) ? 0 : cnt[t-1];
    woff[t] = st;
    gcnt[g*CNTP + t] = st;
  } else if (t < CNTP){
    gcnt[g*CNTP + t] = NSEG;
  }
  __syncthreads();
  #pragma unroll
  for (int u=0;u<5;u++){
    int i = t + u*256;
    if (i < EPG){
      int pos = atomicAdd(&woff[ed[u]], 1);
      slots[pos] = (unsigned short)es[u];
    }
  }
  if (t < NPG){
    int pos = atomicAdd(&woff[t], 1);
    slots[pos] = (unsigned short)t;
  }
  __syncthreads();
  for (int i=t; i<NSEG/8; i+=256)        // 171 coalesced 16B chunks
    *(int4*)(gsrc + (size_t)g*NSEG + i*8) = *(const int4*)&slots[i*8];
}

// ---- GEMM: H[M,192] = A[M,K] @ W  (unchanged from R3) ----
template<int K, bool A_BF16>
__global__ __launch_bounds__(256) void gemm_mfma(const void* __restrict__ Ap,
    const unsigned short* __restrict__ Bt, unsigned short* __restrict__ H){
  __shared__ unsigned short lA[64*K];
  __shared__ unsigned short lB[96*K];
  const int t  = threadIdx.x;
  const int m0 = blockIdx.x*64, c0 = blockIdx.y*96;

  if (A_BF16){
    const unsigned short* A = (const unsigned short*)Ap + (size_t)m0*K;
    const int CH = 64*K/8;
    for (int i=t; i<CH; i+=256){
      int o   = i*16;
      int row = o / (2*K);
      int db  = o - row*(2*K);
      int sc  = (db>>4) ^ (row&7);
      gload_lds16(A + (size_t)row*K + sc*8, lA + (size_t)(i-(t&63))*8);
    }
  } else {
    const float* A = (const float*)Ap;
    const int KC = K/8;
    for (int i=t; i<64*KC; i+=256){
      int row = i/KC, c8 = i - row*KC;
      const float* p = A + (size_t)(m0+row)*K + c8*8;
      float4 v0 = *(const float4*)p;
      float4 v1 = *(const float4*)(p+4);
      short8v pk;
      pk[0]=(short)f2bf(v0.x); pk[1]=(short)f2bf(v0.y); pk[2]=(short)f2bf(v0.z); pk[3]=(short)f2bf(v0.w);
      pk[4]=(short)f2bf(v1.x); pk[5]=(short)f2bf(v1.y); pk[6]=(short)f2bf(v1.z); pk[7]=(short)f2bf(v1.w);
      *(short8v*)((char*)lA + row*(2*K) + ((c8*16) ^ ((row&7)<<4))) = pk;
    }
  }
  {
    const unsigned short* Bg = Bt + (size_t)c0*K;
    const int CH = 96*K/8;
    for (int i=t; i<CH; i+=256){
      int o   = i*16;
      int row = o / (2*K);
      int db  = o - row*(2*K);
      int sc  = (db>>4) ^ (row&7);
      gload_lds16(Bg + (size_t)row*K + sc*8, lB + (size_t)(i-(t&63))*8);
    }
  }
  __syncthreads();

  const int wid = t>>6, l = t&63;
  const int wr = wid>>1, wc = wid&1;
  const int r16 = l&15, kq = l>>4;
  f32x4 acc[2][3] = {};
  #pragma unroll
  for (int kk=0; kk<K/32; kk++){
    const int chunk = kk*4 + kq;
    short8v af[2], bf[3];
    #pragma unroll
    for (int m=0;m<2;m++){
      int row = wr*32 + m*16 + r16;
      af[m] = *(const short8v*)((const char*)lA + row*(2*K) + ((chunk*16) ^ ((row&7)<<4)));
    }
    #pragma unroll
    for (int n=0;n<3;n++){
      int col = wc*48 + n*16 + r16;
      bf[n] = *(const short8v*)((const char*)lB + col*(2*K) + ((chunk*16) ^ ((col&7)<<4)));
    }
    #pragma unroll
    for (int m=0;m<2;m++)
      #pragma unroll
      for (int n=0;n<3;n++)
        acc[m][n] = __builtin_amdgcn_mfma_f32_16x16x32_bf16(af[m], bf[n], acc[m][n], 0,0,0);
  }
  const int crow = (l>>4)*4;
  #pragma unroll
  for (int m=0;m<2;m++){
    #pragma unroll
    for (int n=0;n<3;n++){
      int colg = c0 + wc*48 + n*16 + r16;
      #pragma unroll
      for (int r=0;r<4;r++){
        int rowg = m0 + wr*32 + m*16 + crow + r;
        H[(size_t)rowg*CCH + colg] = f2bf(acc[m][n][r]);
      }
    }
  }
}

// ---- fused GAT: CSR from global, logits fused into h-load, softmax inline ----
// one block per (graph, head); 256 threads
template<bool OUT_BF16>
__global__ __launch_bounds__(256) void gat_edge(
    const unsigned short* __restrict__ H,
    const unsigned short* __restrict__ gsrc, const int* __restrict__ gcnt,
    const float* __restrict__ a_src, const float* __restrict__ a_dst,
    const float* __restrict__ bias, const float* __restrict__ gw,
    const float* __restrict__ gb, const float* __restrict__ gms,
    void* __restrict__ OUTp)
{
  __shared__ float hN[NPG*HSTR];                       // 21.9 KB
  __shared__ float als[NPG], ald[NPG];
  __shared__ __align__(16) unsigned short lsrc[NSEG];  // 2.7 KB
  __shared__ __align__(16) int lcnt[CNTP];
  __shared__ float4 ps[8][8];
  __shared__ float4 mred4[8], vred4[8];

  const int t    = threadIdx.x;
  const int g    = blockIdx.x & 511;
  const int hd   = blockIdx.x >> 9;
  const int base = g*NPG;
  const int lane32 = t & 31, grp = t >> 5;

  // stage CSR (async direct-to-LDS)
  {
    const unsigned short* gs = gsrc + (size_t)g*NSEG;
    for (int i=t; i<NSEG/8; i+=256)                   // 171 chunks
      gload_lds16(gs + i*8, lsrc + (size_t)(i-(t&63))*8);
    const int* gc = gcnt + (size_t)g*CNTP;
    if (t < CNTP/4)                                   // 40 chunks
      gload_lds16(gc + t*4, lcnt + (size_t)(t-(t&63))*4);
  }

  // load h (bf16->f32) + fused attention logits
  // thread = (node nb = t>>2, channel-quad c8c = t&3); handles nodes nb, nb+64, nb+128
  const int c8c = t&3, nb = t>>2;
  const int ab = hd*HID + c8c*8;
  const float4 avs0 = *(const float4*)&a_src[ab];
  const float4 avs1 = *(const float4*)&a_src[ab+4];
  const float4 avd0 = *(const float4*)&a_dst[ab];
  const float4 avd1 = *(const float4*)&a_dst[ab+4];
  #pragma unroll
  for (int it=0; it<3; it++){
    int n = nb + it*64;
    if (n < NPG){
      int4 v = *(const int4*)(H + (size_t)(base+n)*CCH + hd*HID + c8c*8);
      uint32_t w0=(uint32_t)v.x, w1=(uint32_t)v.y, w2=(uint32_t)v.z, w3=(uint32_t)v.w;
      float4 lo = { bitsf(w0<<16), bitsf(w0&0xffff0000u), bitsf(w1<<16), bitsf(w1&0xffff0000u) };
      float4 hi = { bitsf(w2<<16), bitsf(w2&0xffff0000u), bitsf(w3<<16), bitsf(w3&0xffff0000u) };
      float* dst = &hN[n*HSTR + c8c*8];
      *(float4*)dst = lo;
      *(float4*)(dst+4) = hi;
      float s1 = lo.x*avs0.x + lo.y*avs0.y + lo.z*avs0.z + lo.w*avs0.w
               + hi.x*avs1.x + hi.y*avs1.y + hi.z*avs1.z + hi.w*avs1.w;
      float s2 = lo.x*avd0.x + lo.y*avd0.y + lo.z*avd0.z + lo.w*avd0.w
               + hi.x*avd1.x + hi.y*avd1.y + hi.z*avd1.z + hi.w*avd1.w;
      s1 += __shfl_xor(s1, 1); s1 += __shfl_xor(s1, 2);
      s2 += __shfl_xor(s2, 1); s2 += __shfl_xor(s2, 2);
      if (c8c == 0){ als[n] = s1; ald[n] = s2; }
    }
  }
  __syncthreads();

  // aggregation: 32 owners x 8 lanes (lane = channel quad); softmax inline
  const int sub = (lane32>>3)&3;
  const int c8  = lane32&7;
  const int o   = grp*4 + sub;           // owner 0..31; nodes o, o+32, ..., o+128
  float4 acc[5]; float den[5]; int stq[5], lnq[5]; float aldn[5];
  #pragma unroll
  for (int q=0;q<5;q++){
    int n = o + q*32;
    int st=0, en=0; float ad=0.f;
    if (n < NPG){ st = lcnt[n]; en = lcnt[n+1]; ad = ald[n]; }
    stq[q]=st; lnq[q]=en-st; aldn[q]=ad;
    acc[q] = float4{0.f,0.f,0.f,0.f}; den[q]=0.f;
  }
  #pragma unroll
  for (int q=0;q<5;q++){
    int st=stq[q], len=lnq[q];
    float ad = aldn[q];
    int rounds = (len+3)>>2;
    for (int r=0;r<rounds;++r){
      #pragma unroll
      for (int u=0;u<4;u++){
        int j = r*4+u;
        int idx = st + ((j<len)? j : 0);
        int s = (int)lsrc[idx];
        float e = als[s] + ad;
        e = (e>0.f) ? e : 0.2f*e;
        float ex = __expf(e);
        if (j>=len) ex = 0.f;
        const float4 hv = *(const float4*)&hN[s*HSTR + c8*4];
        den[q] += ex;
        acc[q].x = fmaf(ex, hv.x, acc[q].x);
        acc[q].y = fmaf(ex, hv.y, acc[q].y);
        acc[q].z = fmaf(ex, hv.z, acc[q].z);
        acc[q].w = fmaf(ex, hv.w, acc[q].w);
      }
    }
  }

  // epilogue: /denom + bias + ELU, then GraphNorm over 152 nodes per channel
  const int cb = hd*HID + c8*4;
  const float4 bs4 = *(const float4*)&bias[cb];
  const float4 gw4 = *(const float4*)&gw[cb];
  const float4 gb4 = *(const float4*)&gb[cb];
  const float4 ms4 = *(const float4*)&gms[cb];

  float4 outv[5];
  float4 psum = {0.f,0.f,0.f,0.f};
  #pragma unroll
  for (int q=0;q<5;q++){
    int n = o + q*32;
    float4 x = {0.f,0.f,0.f,0.f};
    if (n < NPG){
      float inv = 1.f/den[q];
      x.x = acc[q].x*inv + bs4.x;  x.y = acc[q].y*inv + bs4.y;
      x.z = acc[q].z*inv + bs4.z;  x.w = acc[q].w*inv + bs4.w;
      x.x = (x.x>0.f)?x.x:(__expf(x.x)-1.f);
      x.y = (x.y>0.f)?x.y:(__expf(x.y)-1.f);
      x.z = (x.z>0.f)?x.z:(__expf(x.z)-1.f);
      x.w = (x.w>0.f)?x.w:(__expf(x.w)-1.f);
      psum.x+=x.x; psum.y+=x.y; psum.z+=x.z; psum.w+=x.w;
    }
    outv[q]=x;
  }
  psum.x += __shfl_xor(psum.x, 8, 32); psum.y += __shfl_xor(psum.y, 8, 32);
  psum.z += __shfl_xor(psum.z, 8, 32); psum.w += __shfl_xor(psum.w, 8, 32);
  psum.x += __shfl_xor(psum.x,16, 32); psum.y += __shfl_xor(psum.y,16, 32);
  psum.z += __shfl_xor(psum.z,16, 32); psum.w += __shfl_xor(psum.w,16, 32);
  if (sub==0) ps[grp][c8] = psum;
  __syncthreads();
  if (t < 8){
    float4 m = {0.f,0.f,0.f,0.f};
    #pragma unroll
    for (int q=0;q<8;q++){ float4 v=ps[q][t]; m.x+=v.x; m.y+=v.y; m.z+=v.z; m.w+=v.w; }
    m.x*=(1.f/152.f); m.y*=(1.f/152.f); m.z*=(1.f/152.f); m.w*=(1.f/152.f);
    mred4[t] = m;
  }
  __syncthreads();
  const float4 mean4 = mred4[c8];
  float4 v2 = {0.f,0.f,0.f,0.f};
  #pragma unroll
  for (int q=0;q<5;q++){
    int n = o + q*32;
    if (n < NPG){
      outv[q].x -= mean4.x*ms4.x; outv[q].y -= mean4.y*ms4.y;
      outv[q].z -= mean4.z*ms4.z; outv[q].w -= mean4.w*ms4.w;
      v2.x = fmaf(outv[q].x,outv[q].x,v2.x); v2.y = fmaf(outv[q].y,outv[q].y,v2.y);
      v2.z = fmaf(outv[q].z,outv[q].z,v2.z); v2.w = fmaf(outv[q].w,outv[q].w,v2.w);
    }
  }
  v2.x += __shfl_xor(v2.x, 8, 32); v2.y += __shfl_xor(v2.y, 8, 32);
  v2.z += __shfl_xor(v2.z, 8, 32); v2.w += __shfl_xor(v2.w, 8, 32);
  v2.x += __shfl_xor(v2.x,16, 32); v2.y += __shfl_xor(v2.y,16, 32);
  v2.z += __shfl_xor(v2.z,16, 32); v2.w += __shfl_xor(v2.w,16, 32);
  if (sub==0) ps[grp][c8] = v2;
  __syncthreads();
  if (t < 8){
    float4 s = {0.f,0.f,0.f,0.f};
    #pragma unroll
    for (int q=0;q<8;q++){ float4 v=ps[q][t]; s.x+=v.x; s.y+=v.y; s.z+=v.z; s.w+=v.w; }
    float4 rv;
    rv.x = rsqrtf(s.x*(1.f/152.f)+1e-5f); rv.y = rsqrtf(s.y*(1.f/152.f)+1e-5f);
    rv.z = rsqrtf(s.z*(1.f/152.f)+1e-5f); rv.w = rsqrtf(s.w*(1.f/152.f)+1e-5f);
    vred4[t] = rv;
  }
  __syncthreads();
  const float4 rs4 = vred4[c8];
  #pragma unroll
  for (int q=0;q<5;q++){
    int n = o + q*32;
    if (n < NPG){
      float4 x = outv[q];
      x.x = x.x*rs4.x*gw4.x + gb4.x;  x.y = x.y*rs4.y*gw4.y + gb4.y;
      x.z = x.z*rs4.z*gw4.z + gb4.z;  x.w = x.w*rs4.w*gw4.w + gb4.w;
      size_t oidx = (size_t)(base+n)*CCH + cb;
      if (OUT_BF16){
        ushort4v pk = { f2bf(x.x), f2bf(x.y), f2bf(x.z), f2bf(x.w) };
        *(ushort4v*)((unsigned short*)OUTp + oidx) = pk;
      } else {
        *(float4*)((float*)OUTp + oidx) = x;
      }
    }
  }
}

extern "C" void kernel_launch(void* const* d_in, const int* in_sizes, int n_in,
                              void* d_out, int out_size, void* d_ws, size_t ws_size,
                              hipStream_t stream){
  (void)in_sizes; (void)n_in; (void)out_size; (void)ws_size;
  const float* x    = (const float*)d_in[0];
  const int*   ei   = (const int*)  d_in[1];
  const float* W1   = (const float*)d_in[3];
  const float* as1  = (const float*)d_in[4];
  const float* ad1  = (const float*)d_in[5];
  const float* b1   = (const float*)d_in[6];
  const float* W2   = (const float*)d_in[7];
  const float* as2  = (const float*)d_in[8];
  const float* ad2  = (const float*)d_in[9];
  const float* b2   = (const float*)d_in[10];
  const float* gw1  = (const float*)d_in[11];
  const float* gb1  = (const float*)d_in[12];
  const float* gms1 = (const float*)d_in[13];
  const float* gw2  = (const float*)d_in[14];
  const float* gb2  = (const float*)d_in[15];
  const float* gms2 = (const float*)d_in[16];
  const int* esrc = ei;
  const int* edst = ei + NEDGE;

  char* ws = (char*)d_ws;
  unsigned short* Hbuf = (unsigned short*)ws;                               // [N,192] bf16
  unsigned short* Obuf = (unsigned short*)(ws + (size_t)NNODES*CCH*2);      // [N,192] bf16
  unsigned short* Wt1  = (unsigned short*)(ws + (size_t)NNODES*CCH*4);      // [192,128] bf16
  unsigned short* Wt2  = Wt1 + CCH*128;                                     // [192,192] bf16
  unsigned short* gsrc = Wt2 + CCH*192;                                     // [512,1368] u16
  int*            gcnt = (int*)(gsrc + (size_t)NGRAPH*NSEG);                // [512,160] i32

  csr_build<<<NGRAPH, 256, 0, stream>>>(esrc, edst, gsrc, gcnt);
  wprep_all<<<(CCH*(128+192)+255)/256, 256, 0, stream>>>(W1, W2, Wt1, Wt2);

  gemm_mfma<128,false><<<dim3(NNODES/64,2), 256, 0, stream>>>((const void*)x, Wt1, Hbuf);
  gat_edge<true><<<NGRAPH*HEADS, 256, 0, stream>>>(Hbuf, gsrc, gcnt, as1, ad1, b1, gw1, gb1, gms1, (void*)Obuf);
  gemm_mfma<192,true><<<dim3(NNODES/64,2), 256, 0, stream>>>((const void*)Obuf, Wt2, Hbuf);
  gat_edge<false><<<NGRAPH*HEADS, 256, 0, stream>>>(Hbuf, gsrc, gcnt, as2, ad2, b2, gw2, gb2, gms2, d_out);
}